// Round 11
// baseline (131.293 us; speedup 1.0000x reference)
//
#include <hip/hip_runtime.h>
#include <stdint.h>

#define DEVI __device__ __forceinline__

typedef __attribute__((ext_vector_type(8))) short bf16x8;
typedef __attribute__((ext_vector_type(4))) float f32x4;
typedef __attribute__((ext_vector_type(4))) unsigned short u16x4;
typedef __attribute__((ext_vector_type(4))) float float4v;

DEVI unsigned short f2bf(float f) {
  unsigned int u = __builtin_bit_cast(unsigned int, f);
  u += 0x7FFFu + ((u >> 16) & 1u);
  return (unsigned short)(u >> 16);
}
DEVI float bf2f(short s) {
  unsigned int u = ((unsigned int)(unsigned short)s) << 16;
  return __builtin_bit_cast(float, u);
}
DEVI void gload16(const unsigned short* g, unsigned short* l) {
  __builtin_amdgcn_global_load_lds(
      (const __attribute__((address_space(1))) unsigned int*)g,
      (__attribute__((address_space(3))) unsigned int*)l, 16, 0, 0);
}

// ---------------- K1: x -> Xbf + xT (vectorized); weights at z==8/9 --------
__global__ void cast_prep(const float* __restrict__ x,
                          unsigned short* __restrict__ Xbf,
                          unsigned short* __restrict__ xT,
                          const float* __restrict__ Wqkv,
                          unsigned short* __restrict__ Wqk,
                          unsigned short* __restrict__ WvT,
                          const float* __restrict__ Wproj,
                          unsigned short* __restrict__ WpBf) {
  __shared__ float tls[64 * 129];
  const int t = threadIdx.x;
  if (blockIdx.z < 8) {
    const int n0 = blockIdx.x * 128, c0 = blockIdx.y * 64, b = blockIdx.z;
    const int c8 = (t & 7) * 8;  // 8 consecutive channels per lane
    const int nl = t >> 3;       // 0..31
#pragma unroll
    for (int i = 0; i < 4; ++i) {
      const int n = i * 32 + nl;
      const size_t gi = ((size_t)b * 4096 + n0 + n) * 512 + c0 + c8;
      float4v f0 = *(const float4v*)&x[gi];
      float4v f1 = *(const float4v*)&x[gi + 4];
      bf16x8 o;
      o[0] = (short)f2bf(f0.x); o[1] = (short)f2bf(f0.y);
      o[2] = (short)f2bf(f0.z); o[3] = (short)f2bf(f0.w);
      o[4] = (short)f2bf(f1.x); o[5] = (short)f2bf(f1.y);
      o[6] = (short)f2bf(f1.z); o[7] = (short)f2bf(f1.w);
      *(bf16x8*)&Xbf[gi] = o;
      tls[(c8 + 0) * 129 + n] = f0.x;
      tls[(c8 + 1) * 129 + n] = f0.y;
      tls[(c8 + 2) * 129 + n] = f0.z;
      tls[(c8 + 3) * 129 + n] = f0.w;
      tls[(c8 + 4) * 129 + n] = f1.x;
      tls[(c8 + 5) * 129 + n] = f1.y;
      tls[(c8 + 6) * 129 + n] = f1.z;
      tls[(c8 + 7) * 129 + n] = f1.w;
    }
    __syncthreads();
    const int cr = t >> 2, nq = t & 3;
#pragma unroll
    for (int ii = 0; ii < 4; ++ii) {
      const int n = nq * 8 + ii * 32;
      bf16x8 o;
#pragma unroll
      for (int s = 0; s < 8; ++s) o[s] = (short)f2bf(tls[cr * 129 + n + s]);
      *(bf16x8*)&xT[((size_t)b * 512 + c0 + cr) * 4096 + n0 + n] = o;
    }
    return;
  }
  if (blockIdx.z == 9) {  // cast Wproj -> bf16
    const int id = blockIdx.y * 32 + blockIdx.x;  // 0..255
    const int i = id * 256 + t;                   // 65536 u16x4 total
    float4v f = ((const float4v*)Wproj)[i];
    u16x4 o;
    o.x = f2bf(f.x); o.y = f2bf(f.y); o.z = f2bf(f.z); o.w = f2bf(f.w);
    ((u16x4*)WpBf)[i] = o;
    return;
  }
  const int id = blockIdx.y * 32 + blockIdx.x;  // 0..255
  {
    const float4v* src = (const float4v*)Wqkv;
    u16x4* dst = (u16x4*)Wqk;
    int base = id * 512 + t;
#pragma unroll
    for (int j = 0; j < 2; ++j) {
      int i = base + j * 256;
      float4v f = src[i];
      u16x4 o;
      o.x = f2bf(f.x); o.y = f2bf(f.y); o.z = f2bf(f.z); o.w = f2bf(f.w);
      dst[i] = o;
    }
  }
  if (id < 64) {
    const int tr = id >> 3, tc = id & 7;
    const int c = t & 63, rb = t >> 6;
    __syncthreads();
#pragma unroll
    for (int rr = 0; rr < 16; ++rr) {
      int r = rb * 16 + rr;
      tls[r * 65 + c] = Wqkv[(size_t)(1024 + tr * 64 + r) * 512 + tc * 64 + c];
    }
    __syncthreads();
#pragma unroll
    for (int rr = 0; rr < 16; ++rr) {
      int j = rb * 16 + rr;
      WvT[(size_t)(tc * 64 + j) * 512 + tr * 64 + c] = f2bf(tls[c * 65 + j]);
    }
  }
}

// ============ 256x256 8-wave counted-vmcnt GEMM mainloop (BK=64) ===========
#define STAGE256(kt)                                                         \
  {                                                                          \
    const int bo_ = ((kt) & 1) * 16384;                                      \
    _Pragma("unroll") for (int i_ = 0; i_ < 4; ++i_) {                       \
      gload16(pA + (size_t)i_ * 64 * strideA + (kt) * 64,                    \
              ldsA + bo_ + i_ * 4096 + wave * 512);                          \
      gload16(pB + (size_t)i_ * 64 * strideB + (kt) * 64,                    \
              ldsB + bo_ + i_ * 4096 + wave * 512);                          \
    }                                                                        \
  }

template <int NT>
DEVI void gemm256_loop(const unsigned short* pA, size_t strideA,
                       const unsigned short* pB, size_t strideB,
                       unsigned short* ldsA, unsigned short* ldsB,
                       int wave, int lane, f32x4 acc[8][4]) {
  const int wr = wave >> 2, wc = wave & 3;
  const int fr = lane & 15, kg = lane >> 4;
  const int x0 = ((kg * 16) ^ ((fr & 7) << 4)) >> 1;
  const int x1 = ((64 + kg * 16) ^ ((fr & 7) << 4)) >> 1;
  STAGE256(0);
  for (int kt = 0; kt < NT; ++kt) {
    __builtin_amdgcn_s_barrier();
    __builtin_amdgcn_sched_barrier(0);
    if (kt + 1 < NT) {
      STAGE256(kt + 1);
      asm volatile("s_waitcnt vmcnt(8)" ::: "memory");
    } else {
      asm volatile("s_waitcnt vmcnt(0)" ::: "memory");
    }
    __builtin_amdgcn_sched_barrier(0);
    __builtin_amdgcn_s_barrier();
    __builtin_amdgcn_sched_barrier(0);
    const int bo = (kt & 1) * 16384;
    bf16x8 bfrag[4][2];
#pragma unroll
    for (int n = 0; n < 4; ++n) {
      const int ro = (wc * 64 + n * 16 + fr) * 64;
      bfrag[n][0] = *(const bf16x8*)&ldsB[bo + ro + x0];
      bfrag[n][1] = *(const bf16x8*)&ldsB[bo + ro + x1];
    }
#pragma unroll
    for (int mp = 0; mp < 4; ++mp) {
      bf16x8 af[2][2];
#pragma unroll
      for (int mi = 0; mi < 2; ++mi) {
        const int ro = (wr * 128 + (mp * 2 + mi) * 16 + fr) * 64;
        af[mi][0] = *(const bf16x8*)&ldsA[bo + ro + x0];
        af[mi][1] = *(const bf16x8*)&ldsA[bo + ro + x1];
      }
      __builtin_amdgcn_s_setprio(1);
#pragma unroll
      for (int mi = 0; mi < 2; ++mi)
#pragma unroll
        for (int n = 0; n < 4; ++n) {
          acc[mp * 2 + mi][n] = __builtin_amdgcn_mfma_f32_16x16x32_bf16(
              af[mi][0], bfrag[n][0], acc[mp * 2 + mi][n], 0, 0, 0);
          acc[mp * 2 + mi][n] = __builtin_amdgcn_mfma_f32_16x16x32_bf16(
              af[mi][1], bfrag[n][1], acc[mp * 2 + mi][n], 0, 0, 0);
        }
      __builtin_amdgcn_s_setprio(0);
    }
  }
}

// ------- K2: G_b = xT_b @ xT_b^T, 256^2 tiles, 8 chunks, XCD-swizzled ------
__launch_bounds__(512, 2)
__global__ void gsyrk(const unsigned short* __restrict__ xT,
                      unsigned short* __restrict__ Gpart) {
  __shared__ __align__(16) unsigned short ldsA[2 * 16384];
  __shared__ __align__(16) unsigned short ldsB[2 * 16384];
  int fl = blockIdx.x + 4 * (blockIdx.y + 8 * blockIdx.z);
  fl = (fl & 7) * 32 + (fl >> 3);  // b = dispatch_id % 8 -> XCD-local
  const int quad = fl & 3, chunk = (fl >> 2) & 7, b = fl >> 5;
  const int tid = threadIdx.x, wave = tid >> 6, lane = tid & 63;
  const int tc = quad >> 1, td = quad & 1;
  const unsigned short* xb = xT + (size_t)b * 512 * 4096 + chunk * 512;
  const int sRow = tid >> 3;
  const int kEl = 8 * ((tid & 7) ^ ((tid >> 3) & 7));
  const unsigned short* pA = xb + (size_t)(tc * 256 + sRow) * 4096 + kEl;
  const unsigned short* pB = xb + (size_t)(td * 256 + sRow) * 4096 + kEl;
  f32x4 acc[8][4] = {};
  gemm256_loop<8>(pA, 4096, pB, 4096, ldsA, ldsB, wave, lane, acc);
  const int wr = wave >> 2, wc = wave & 3;
  const int fr = lane & 15, kg = lane >> 4;
  unsigned short* Gp = Gpart + (size_t)(chunk * 8 + b) * 512 * 512;
#pragma unroll
  for (int m = 0; m < 8; ++m) {
    const int row0 = tc * 256 + wr * 128 + m * 16 + kg * 4;
#pragma unroll
    for (int n = 0; n < 4; ++n) {
      const int col = td * 256 + wc * 64 + n * 16 + fr;
      f32x4 v = acc[m][n];
#pragma unroll
      for (int r = 0; r < 4; ++r)
        Gp[(size_t)(row0 + r) * 512 + col] = f2bf(v[r]);
    }
  }
}

// -------- K3: reduce 8 bf16 split-K partials -> G bf16 (b XCD-local) -------
// Gpart is read-exactly-once: non-temporal loads keep L2 warm for tall_gemm.
__global__ void greduce(const unsigned short* __restrict__ Gpart,
                        unsigned short* __restrict__ Gbf) {
  const int b = blockIdx.x & 7, seg = blockIdx.x >> 3;  // 128 segs per b
  const int t = threadIdx.x;
#pragma unroll
  for (int jj = 0; jj < 2; ++jj) {
    const int j4 = seg * 512 + jj * 256 + t;  // u16x4 index within batch
    float s0 = 0, s1 = 0, s2 = 0, s3 = 0;
#pragma unroll
    for (int c = 0; c < 8; ++c) {
      u16x4 v = __builtin_nontemporal_load(
          (const u16x4*)Gpart + (size_t)(c * 8 + b) * 65536 + j4);
      s0 += bf2f((short)v.x); s1 += bf2f((short)v.y);
      s2 += bf2f((short)v.z); s3 += bf2f((short)v.w);
    }
    u16x4 o;
    o.x = f2bf(s0); o.y = f2bf(s1); o.z = f2bf(s2); o.w = f2bf(s3);
    ((u16x4*)Gbf)[(size_t)b * 65536 + j4] = o;
  }
}

// ------------- 2-phase double-buffered 128x128 mainloop (small GEMMs) ------
template <int KITERS>
DEVI void gemm_db(const unsigned short* gA, int strideA,
                  const unsigned short* gB, int strideB,
                  unsigned short (*lA)[4096], unsigned short (*lB)[4096],
                  int wave, int wr, int wc, int fr, int kg, f32x4 acc[4][4]) {
  const int wo = wave * 512;
#define STAGE_T(buf, kk)                                                    \
  gload16(gA + (kk) * 32, lA[buf] + wo);                                    \
  gload16(gA + (kk) * 32 + (size_t)64 * strideA, lA[buf] + wo + 2048);      \
  gload16(gB + (kk) * 32, lB[buf] + wo);                                    \
  gload16(gB + (kk) * 32 + (size_t)64 * strideB, lB[buf] + wo + 2048);
  STAGE_T(0, 0);
  __syncthreads();
  int cur = 0;
  for (int kk = 1; kk <= KITERS; ++kk) {
    if (kk < KITERS) { STAGE_T(cur ^ 1, kk); }
    bf16x8 af[4], bfv[4];
#pragma unroll
    for (int mi = 0; mi < 4; ++mi)
      af[mi] = *(const bf16x8*)&lA[cur][(wr * 64 + mi * 16 + fr) * 32 + kg * 8];
#pragma unroll
    for (int ni = 0; ni < 4; ++ni)
      bfv[ni] = *(const bf16x8*)&lB[cur][(wc * 64 + ni * 16 + fr) * 32 + kg * 8];
#pragma unroll
    for (int mi = 0; mi < 4; ++mi)
#pragma unroll
      for (int ni = 0; ni < 4; ++ni)
        acc[mi][ni] = __builtin_amdgcn_mfma_f32_16x16x32_bf16(
            af[mi], bfv[ni], acc[mi][ni], 0, 0, 0);
    __syncthreads();
    cur ^= 1;
  }
#undef STAGE_T
}

// ------- K4: T_b = Wqk @ G_b (+ fused sumsq partials), b XCD-local ---------
__launch_bounds__(256)
__global__ void tall_gemm(const unsigned short* __restrict__ Wqk,
                          const unsigned short* __restrict__ Gbf,
                          unsigned short* __restrict__ Tbf,
                          float* __restrict__ ssPart) {
  __shared__ __align__(16) unsigned short lA[2][4096];
  __shared__ __align__(16) unsigned short lB[2][4096];
  __shared__ float ssL[128][2];
  const int tid = threadIdx.x, wave = tid >> 6, lane = tid & 63;
  const int wr = wave >> 1, wc = wave & 1, fr = lane & 15, kg = lane >> 4;
  const int b = blockIdx.x;                  // dispatch_id % 8 == b
  const int colBase = blockIdx.y * 128;
  const int rowBase = blockIdx.z * 128;
  const unsigned short* Gb = Gbf + (size_t)b * 512 * 512;
  f32x4 acc[4][4] = {};
  const int sRow = wave * 16 + (lane >> 2);
  const int sK = (lane & 3) * 8;
  gemm_db<16>(Wqk + (size_t)(rowBase + sRow) * 512 + sK, 512,
              Gb + (size_t)(colBase + sRow) * 512 + sK, 512,
              lA, lB, wave, wr, wc, fr, kg, acc);
  unsigned short* Tb = Tbf + (size_t)b * 1024 * 512;
  const bool wT = rowBase < 512;
#pragma unroll
  for (int mi = 0; mi < 4; ++mi) {
    const int rbase = rowBase + wr * 64 + mi * 16 + kg * 4;
    f32x4 sacc = {0.f, 0.f, 0.f, 0.f};
#pragma unroll
    for (int ni = 0; ni < 4; ++ni) {
      const int col = colBase + wc * 64 + ni * 16 + fr;
      f32x4 v = acc[mi][ni];
#pragma unroll
      for (int r = 0; r < 4; ++r) {
        float w = bf2f((short)Wqk[(size_t)(rbase + r) * 512 + col]);
        if (wT) Tb[(size_t)(rbase + r) * 512 + col] = f2bf(v[r]);
        sacc[r] += v[r] * w;
      }
    }
#pragma unroll
    for (int o = 1; o < 16; o <<= 1) {
#pragma unroll
      for (int r = 0; r < 4; ++r) sacc[r] += __shfl_xor(sacc[r], o);
    }
    if (fr == 0) {
#pragma unroll
      for (int r = 0; r < 4; ++r)
        ssL[wr * 64 + mi * 16 + kg * 4 + r][wc] = sacc[r];
    }
  }
  __syncthreads();
  if (tid < 128)
    ssPart[((size_t)blockIdx.y * 8 + b) * 1024 + rowBase + tid] =
        ssL[tid][0] + ssL[tid][1];
}

// ------ K5: fused S = T_q @ Wk^T -> softmax -> Weff = Wproj_h @ attn -------
__global__ void s_softmax(const unsigned short* __restrict__ Tbf,
                          const unsigned short* __restrict__ Wqk,
                          const float* __restrict__ ssPart,
                          const float* __restrict__ temp,
                          const unsigned short* __restrict__ WpBf,
                          unsigned short* __restrict__ Weff) {
  __shared__ float Sl[64 * 64];
  __shared__ float invq[64], invk[64];
  __shared__ __align__(16) unsigned short atT[64 * 72];  // attn^T bf16
  const int bh = blockIdx.x, b = bh & 7, h = bh >> 3;  // b XCD-local
  const unsigned short* qbase = Tbf + (size_t)(b * 1024 + h * 64) * 512;
  const unsigned short* kbase = Wqk + (size_t)(512 + h * 64) * 512;
  const int t = threadIdx.x;
  const int wave = t >> 6, lane = t & 63;
  const int wr = wave >> 1, wc = wave & 1, fr = lane & 15, kg = lane >> 4;
  f32x4 acc[2][2] = {};
  for (int kk = 0; kk < 512; kk += 32) {
    bf16x8 a[2], bb[2];
#pragma unroll
    for (int mi = 0; mi < 2; ++mi)
      a[mi] = *(const bf16x8*)(qbase + (size_t)(wr * 32 + mi * 16 + fr) * 512 + kk + kg * 8);
#pragma unroll
    for (int ni = 0; ni < 2; ++ni)
      bb[ni] = *(const bf16x8*)(kbase + (size_t)(wc * 32 + ni * 16 + fr) * 512 + kk + kg * 8);
#pragma unroll
    for (int mi = 0; mi < 2; ++mi)
#pragma unroll
      for (int ni = 0; ni < 2; ++ni)
        acc[mi][ni] = __builtin_amdgcn_mfma_f32_16x16x32_bf16(a[mi], bb[ni], acc[mi][ni], 0, 0, 0);
  }
#pragma unroll
  for (int mi = 0; mi < 2; ++mi)
#pragma unroll
    for (int ni = 0; ni < 2; ++ni) {
      f32x4 v = acc[mi][ni];
#pragma unroll
      for (int r = 0; r < 4; ++r)
        Sl[(wr * 32 + mi * 16 + kg * 4 + r) * 64 + wc * 32 + ni * 16 + fr] = v[r];
    }
  if (t < 128) {
    const int r = (t >> 6) * 512 + h * 64 + (t & 63);
    float s = 0.f;
#pragma unroll
    for (int nt = 0; nt < 4; ++nt) s += ssPart[((size_t)nt * 8 + b) * 1024 + r];
    float inv = 1.f / fmaxf(sqrtf(s), 1e-12f);
    if (t < 64) invq[t] = inv;
    else invk[t - 64] = inv;
  }
  __syncthreads();
  const float tmp = temp[h];
  const int c = t >> 2, q4 = t & 3;
  float lg[16];
  float mx = -1e30f;
#pragma unroll
  for (int j = 0; j < 16; ++j) {
    const int d = q4 * 16 + j;
    lg[j] = Sl[c * 64 + d] * invq[c] * invk[d] * tmp;
    mx = fmaxf(mx, lg[j]);
  }
  mx = fmaxf(mx, __shfl_xor(mx, 1));
  mx = fmaxf(mx, __shfl_xor(mx, 2));
  float sum = 0.f;
#pragma unroll
  for (int j = 0; j < 16; ++j) {
    lg[j] = __expf(lg[j] - mx);
    sum += lg[j];
  }
  sum += __shfl_xor(sum, 1);
  sum += __shfl_xor(sum, 2);
  const float inv = 1.f / sum;
#pragma unroll
  for (int j = 0; j < 16; ++j)
    atT[(q4 * 16 + j) * 72 + c] = f2bf(lg[j] * inv);  // transposed bf16
  __syncthreads();
  // Weff[e][d] = sum_c WpBf[e][h*64+c] * attn[c][d];  A=[e][c], B=atT[d][c]
  bf16x8 bfrag[4][2];
#pragma unroll
  for (int n = 0; n < 4; ++n)
#pragma unroll
    for (int kk = 0; kk < 2; ++kk)
      bfrag[n][kk] =
          *(const bf16x8*)&atT[(n * 16 + fr) * 72 + kk * 32 + kg * 8];
  unsigned short* We = Weff + (size_t)b * 512 * 512 + h * 64;
#pragma unroll
  for (int m = 0; m < 8; ++m) {
    const int eA = wave * 128 + m * 16 + fr;
    bf16x8 af[2];
#pragma unroll
    for (int kk = 0; kk < 2; ++kk)
      af[kk] = *(const bf16x8*)&WpBf[(size_t)eA * 512 + h * 64 + kk * 32 + kg * 8];
    f32x4 acc4[4] = {};
#pragma unroll
    for (int kk = 0; kk < 2; ++kk)
#pragma unroll
      for (int n = 0; n < 4; ++n)
        acc4[n] = __builtin_amdgcn_mfma_f32_16x16x32_bf16(af[kk], bfrag[n][kk],
                                                          acc4[n], 0, 0, 0);
    const int e0 = wave * 128 + m * 16 + kg * 4;
#pragma unroll
    for (int n = 0; n < 4; ++n)
#pragma unroll
      for (int r = 0; r < 4; ++r)
        We[(size_t)(e0 + r) * 512 + n * 16 + fr] = f2bf(acc4[n][r]);
  }
}

// ------- K6: Wcomb[b] = Weff[b] @ Wv (= Weff · WvT^T), b XCD-local ---------
__launch_bounds__(256)
__global__ void wcomb_gemm(const unsigned short* __restrict__ WeffAll,
                           const unsigned short* __restrict__ WvT,
                           unsigned short* __restrict__ WcombAll) {
  __shared__ __align__(16) unsigned short lA[2][4096];
  __shared__ __align__(16) unsigned short lB[2][4096];
  const int tid = threadIdx.x, wave = tid >> 6, lane = tid & 63;
  const int wr = wave >> 1, wc = wave & 1, fr = lane & 15, kg = lane >> 4;
  const int b = blockIdx.x;  // dispatch_id % 8 == b
  const int colBase = blockIdx.y * 128, rowBase = blockIdx.z * 128;
  const unsigned short* A = WeffAll + (size_t)b * 512 * 512;
  f32x4 acc[4][4] = {};
  const int sRow = wave * 16 + (lane >> 2);
  const int sK = (lane & 3) * 8;
  gemm_db<16>(A + (size_t)(rowBase + sRow) * 512 + sK, 512,
              WvT + (size_t)(colBase + sRow) * 512 + sK, 512,
              lA, lB, wave, wr, wc, fr, kg, acc);
  unsigned short* Wc = WcombAll + (size_t)b * 512 * 512;
#pragma unroll
  for (int mi = 0; mi < 4; ++mi) {
    const int rbase = rowBase + wr * 64 + mi * 16 + kg * 4;
#pragma unroll
    for (int ni = 0; ni < 4; ++ni) {
      const int col = colBase + wc * 64 + ni * 16 + fr;
      f32x4 v = acc[mi][ni];
#pragma unroll
      for (int r = 0; r < 4; ++r)
        Wc[(size_t)(rbase + r) * 512 + col] = f2bf(v[r]);
    }
  }
}

// --------- K7: final = x @ Wcomb[b]^T + bproj (256^2, XCD-swizzled) --------
// out is never re-read on device: non-temporal stores avoid evicting
// Xbf/Wcomb from L2/L3 mid-kernel.
__launch_bounds__(512, 2)
__global__ void out_gemm(const unsigned short* __restrict__ Xbf,
                         const unsigned short* __restrict__ WcombAll,
                         const float* __restrict__ bias,
                         float* __restrict__ out) {
  __shared__ __align__(16) unsigned short ldsA[2 * 16384];
  __shared__ __align__(16) unsigned short ldsB[2 * 16384];
  int fl = blockIdx.x + 16 * (blockIdx.y + 2 * blockIdx.z);
  fl = (fl & 7) * 32 + (fl >> 3);  // b = dispatch_id % 8 -> XCD-local
  const int bxi = fl & 15, byi = (fl >> 4) & 1, b = fl >> 5;
  const int tid = threadIdx.x, wave = tid >> 6, lane = tid & 63;
  const int rowBase = bxi * 256, colBase = byi * 256;
  const unsigned short* A = Xbf + (size_t)b * 4096 * 512;
  const unsigned short* Bw = WcombAll + (size_t)b * 512 * 512;
  const int sRow = tid >> 3;
  const int kEl = 8 * ((tid & 7) ^ ((tid >> 3) & 7));
  const unsigned short* pA = A + (size_t)(rowBase + sRow) * 512 + kEl;
  const unsigned short* pB = Bw + (size_t)(colBase + sRow) * 512 + kEl;
  f32x4 acc[8][4] = {};
  gemm256_loop<8>(pA, 512, pB, 512, ldsA, ldsB, wave, lane, acc);
  const int wr = wave >> 2, wc = wave & 3;
  const int fr = lane & 15, kg = lane >> 4;
#pragma unroll
  for (int m = 0; m < 8; ++m) {
    const int row0 = rowBase + wr * 128 + m * 16 + kg * 4;
#pragma unroll
    for (int n = 0; n < 4; ++n) {
      const int col = colBase + wc * 64 + n * 16 + fr;
      const float bcol = bias[col];
      f32x4 v = acc[m][n];
#pragma unroll
      for (int r = 0; r < 4; ++r)
        __builtin_nontemporal_store(
            v[r] + bcol, &out[((size_t)b * 4096 + row0 + r) * 512 + col]);
    }
  }
}

extern "C" void kernel_launch(void* const* d_in, const int* in_sizes, int n_in,
                              void* d_out, int out_size, void* d_ws, size_t ws_size,
                              hipStream_t stream) {
  const float* x = (const float*)d_in[0];      // [8][4096][512]
  const float* Wqkv = (const float*)d_in[1];   // [1536][512]
  const float* Wproj = (const float*)d_in[2];  // [512][512]
  const float* bproj = (const float*)d_in[3];  // [512]
  const float* temp = (const float*)d_in[4];   // [8]
  float* out = (float*)d_out;

  char* ws = (char*)d_ws;
  unsigned short* Xbf = (unsigned short*)(ws + 0);            // 33,554,432
  unsigned short* xT = (unsigned short*)(ws + 33554432);      // 33,554,432
  unsigned short* Wqk = (unsigned short*)(ws + 67108864);     //  1,048,576
  unsigned short* WvT = (unsigned short*)(ws + 68157440);     //    524,288
  unsigned short* Gpart = (unsigned short*)(ws + 68681728);   // 33,554,432
  unsigned short* Gbf = (unsigned short*)(ws + 102236160);    //  4,194,304
  unsigned short* Tbf = (unsigned short*)(ws + 106430464);    //  8,388,608
  float* ssPart = (float*)(ws + 114819072);                   //    131,072
  unsigned short* Weff = (unsigned short*)(ws + 115998720);   //  4,194,304
  unsigned short* Wcomb = (unsigned short*)(ws + 120193024);  //  4,194,304
  unsigned short* WpBf = (unsigned short*)(ws + 124387328);   //    524,288
  // total: 124,911,616 B

  cast_prep<<<dim3(32, 8, 10), 256, 0, stream>>>(x, Xbf, xT, Wqkv, Wqk, WvT,
                                                 Wproj, WpBf);
  gsyrk<<<dim3(4, 8, 8), 512, 0, stream>>>(xT, Gpart);
  greduce<<<1024, 256, 0, stream>>>(Gpart, Gbf);
  tall_gemm<<<dim3(8, 4, 8), 256, 0, stream>>>(Wqk, Gbf, Tbf, ssPart);
  s_softmax<<<64, 256, 0, stream>>>(Tbf, Wqk, ssPart, temp, WpBf, Weff);
  wcomb_gemm<<<dim3(8, 4, 4), 256, 0, stream>>>(Weff, WvT, Wcomb);
  out_gemm<<<dim3(16, 2, 8), 512, 0, stream>>>(Xbf, Wcomb, bproj, out);
}

// Round 12
// 122.953 us; speedup vs baseline: 1.0678x; 1.0678x over previous
//
#include <hip/hip_runtime.h>
#include <stdint.h>

#define DEVI __device__ __forceinline__

typedef __attribute__((ext_vector_type(8))) short bf16x8;
typedef __attribute__((ext_vector_type(4))) float f32x4;
typedef __attribute__((ext_vector_type(4))) unsigned short u16x4;
typedef __attribute__((ext_vector_type(4))) float float4v;

DEVI unsigned short f2bf(float f) {
  unsigned int u = __builtin_bit_cast(unsigned int, f);
  u += 0x7FFFu + ((u >> 16) & 1u);
  return (unsigned short)(u >> 16);
}
DEVI float bf2f(short s) {
  unsigned int u = ((unsigned int)(unsigned short)s) << 16;
  return __builtin_bit_cast(float, u);
}
DEVI void gload16(const unsigned short* g, unsigned short* l) {
  __builtin_amdgcn_global_load_lds(
      (const __attribute__((address_space(1))) unsigned int*)g,
      (__attribute__((address_space(3))) unsigned int*)l, 16, 0, 0);
}

// ---------------- K1: x -> Xbf + xT (vectorized); weights at z==8/9 --------
__global__ void cast_prep(const float* __restrict__ x,
                          unsigned short* __restrict__ Xbf,
                          unsigned short* __restrict__ xT,
                          const float* __restrict__ Wqkv,
                          unsigned short* __restrict__ Wqk,
                          unsigned short* __restrict__ WvT,
                          const float* __restrict__ Wproj,
                          unsigned short* __restrict__ WpBf) {
  __shared__ float tls[64 * 129];
  const int t = threadIdx.x;
  if (blockIdx.z < 8) {
    const int n0 = blockIdx.x * 128, c0 = blockIdx.y * 64, b = blockIdx.z;
    const int c8 = (t & 7) * 8;  // 8 consecutive channels per lane
    const int nl = t >> 3;       // 0..31
#pragma unroll
    for (int i = 0; i < 4; ++i) {
      const int n = i * 32 + nl;
      const size_t gi = ((size_t)b * 4096 + n0 + n) * 512 + c0 + c8;
      float4v f0 = *(const float4v*)&x[gi];
      float4v f1 = *(const float4v*)&x[gi + 4];
      bf16x8 o;
      o[0] = (short)f2bf(f0.x); o[1] = (short)f2bf(f0.y);
      o[2] = (short)f2bf(f0.z); o[3] = (short)f2bf(f0.w);
      o[4] = (short)f2bf(f1.x); o[5] = (short)f2bf(f1.y);
      o[6] = (short)f2bf(f1.z); o[7] = (short)f2bf(f1.w);
      *(bf16x8*)&Xbf[gi] = o;
      tls[(c8 + 0) * 129 + n] = f0.x;
      tls[(c8 + 1) * 129 + n] = f0.y;
      tls[(c8 + 2) * 129 + n] = f0.z;
      tls[(c8 + 3) * 129 + n] = f0.w;
      tls[(c8 + 4) * 129 + n] = f1.x;
      tls[(c8 + 5) * 129 + n] = f1.y;
      tls[(c8 + 6) * 129 + n] = f1.z;
      tls[(c8 + 7) * 129 + n] = f1.w;
    }
    __syncthreads();
    const int cr = t >> 2, nq = t & 3;
#pragma unroll
    for (int ii = 0; ii < 4; ++ii) {
      const int n = nq * 8 + ii * 32;
      bf16x8 o;
#pragma unroll
      for (int s = 0; s < 8; ++s) o[s] = (short)f2bf(tls[cr * 129 + n + s]);
      *(bf16x8*)&xT[((size_t)b * 512 + c0 + cr) * 4096 + n0 + n] = o;
    }
    return;
  }
  if (blockIdx.z == 9) {  // cast Wproj -> bf16
    const int id = blockIdx.y * 32 + blockIdx.x;  // 0..255
    const int i = id * 256 + t;                   // 65536 u16x4 total
    float4v f = ((const float4v*)Wproj)[i];
    u16x4 o;
    o.x = f2bf(f.x); o.y = f2bf(f.y); o.z = f2bf(f.z); o.w = f2bf(f.w);
    ((u16x4*)WpBf)[i] = o;
    return;
  }
  const int id = blockIdx.y * 32 + blockIdx.x;  // 0..255
  {
    const float4v* src = (const float4v*)Wqkv;
    u16x4* dst = (u16x4*)Wqk;
    int base = id * 512 + t;
#pragma unroll
    for (int j = 0; j < 2; ++j) {
      int i = base + j * 256;
      float4v f = src[i];
      u16x4 o;
      o.x = f2bf(f.x); o.y = f2bf(f.y); o.z = f2bf(f.z); o.w = f2bf(f.w);
      dst[i] = o;
    }
  }
  if (id < 64) {
    const int tr = id >> 3, tc = id & 7;
    const int c = t & 63, rb = t >> 6;
    __syncthreads();
#pragma unroll
    for (int rr = 0; rr < 16; ++rr) {
      int r = rb * 16 + rr;
      tls[r * 65 + c] = Wqkv[(size_t)(1024 + tr * 64 + r) * 512 + tc * 64 + c];
    }
    __syncthreads();
#pragma unroll
    for (int rr = 0; rr < 16; ++rr) {
      int j = rb * 16 + rr;
      WvT[(size_t)(tc * 64 + j) * 512 + tr * 64 + c] = f2bf(tls[c * 65 + j]);
    }
  }
}

// ============ 256x256 8-wave counted-vmcnt GEMM mainloop (BK=64) ===========
#define STAGE256(kt)                                                         \
  {                                                                          \
    const int bo_ = ((kt) & 1) * 16384;                                      \
    _Pragma("unroll") for (int i_ = 0; i_ < 4; ++i_) {                       \
      gload16(pA + (size_t)i_ * 64 * strideA + (kt) * 64,                    \
              ldsA + bo_ + i_ * 4096 + wave * 512);                          \
      gload16(pB + (size_t)i_ * 64 * strideB + (kt) * 64,                    \
              ldsB + bo_ + i_ * 4096 + wave * 512);                          \
    }                                                                        \
  }

template <int NT>
DEVI void gemm256_loop(const unsigned short* pA, size_t strideA,
                       const unsigned short* pB, size_t strideB,
                       unsigned short* ldsA, unsigned short* ldsB,
                       int wave, int lane, f32x4 acc[8][4]) {
  const int wr = wave >> 2, wc = wave & 3;
  const int fr = lane & 15, kg = lane >> 4;
  const int x0 = ((kg * 16) ^ ((fr & 7) << 4)) >> 1;
  const int x1 = ((64 + kg * 16) ^ ((fr & 7) << 4)) >> 1;
  STAGE256(0);
  for (int kt = 0; kt < NT; ++kt) {
    __builtin_amdgcn_s_barrier();
    __builtin_amdgcn_sched_barrier(0);
    if (kt + 1 < NT) {
      STAGE256(kt + 1);
      asm volatile("s_waitcnt vmcnt(8)" ::: "memory");
    } else {
      asm volatile("s_waitcnt vmcnt(0)" ::: "memory");
    }
    __builtin_amdgcn_sched_barrier(0);
    __builtin_amdgcn_s_barrier();
    __builtin_amdgcn_sched_barrier(0);
    const int bo = (kt & 1) * 16384;
    bf16x8 bfrag[4][2];
#pragma unroll
    for (int n = 0; n < 4; ++n) {
      const int ro = (wc * 64 + n * 16 + fr) * 64;
      bfrag[n][0] = *(const bf16x8*)&ldsB[bo + ro + x0];
      bfrag[n][1] = *(const bf16x8*)&ldsB[bo + ro + x1];
    }
#pragma unroll
    for (int mp = 0; mp < 4; ++mp) {
      bf16x8 af[2][2];
#pragma unroll
      for (int mi = 0; mi < 2; ++mi) {
        const int ro = (wr * 128 + (mp * 2 + mi) * 16 + fr) * 64;
        af[mi][0] = *(const bf16x8*)&ldsA[bo + ro + x0];
        af[mi][1] = *(const bf16x8*)&ldsA[bo + ro + x1];
      }
      __builtin_amdgcn_s_setprio(1);
#pragma unroll
      for (int mi = 0; mi < 2; ++mi)
#pragma unroll
        for (int n = 0; n < 4; ++n) {
          acc[mp * 2 + mi][n] = __builtin_amdgcn_mfma_f32_16x16x32_bf16(
              af[mi][0], bfrag[n][0], acc[mp * 2 + mi][n], 0, 0, 0);
          acc[mp * 2 + mi][n] = __builtin_amdgcn_mfma_f32_16x16x32_bf16(
              af[mi][1], bfrag[n][1], acc[mp * 2 + mi][n], 0, 0, 0);
        }
      __builtin_amdgcn_s_setprio(0);
    }
  }
}

// ------- K2: G_b = xT_b @ xT_b^T, 256^2 tiles, 8 chunks, XCD-swizzled ------
__launch_bounds__(512, 2)
__global__ void gsyrk(const unsigned short* __restrict__ xT,
                      unsigned short* __restrict__ Gpart) {
  __shared__ __align__(16) unsigned short ldsA[2 * 16384];
  __shared__ __align__(16) unsigned short ldsB[2 * 16384];
  int fl = blockIdx.x + 4 * (blockIdx.y + 8 * blockIdx.z);
  fl = (fl & 7) * 32 + (fl >> 3);  // b = dispatch_id % 8 -> XCD-local
  const int quad = fl & 3, chunk = (fl >> 2) & 7, b = fl >> 5;
  const int tid = threadIdx.x, wave = tid >> 6, lane = tid & 63;
  const int tc = quad >> 1, td = quad & 1;
  const unsigned short* xb = xT + (size_t)b * 512 * 4096 + chunk * 512;
  const int sRow = tid >> 3;
  const int kEl = 8 * ((tid & 7) ^ ((tid >> 3) & 7));
  const unsigned short* pA = xb + (size_t)(tc * 256 + sRow) * 4096 + kEl;
  const unsigned short* pB = xb + (size_t)(td * 256 + sRow) * 4096 + kEl;
  f32x4 acc[8][4] = {};
  gemm256_loop<8>(pA, 4096, pB, 4096, ldsA, ldsB, wave, lane, acc);
  const int wr = wave >> 2, wc = wave & 3;
  const int fr = lane & 15, kg = lane >> 4;
  unsigned short* Gp = Gpart + (size_t)(chunk * 8 + b) * 512 * 512;
#pragma unroll
  for (int m = 0; m < 8; ++m) {
    const int row0 = tc * 256 + wr * 128 + m * 16 + kg * 4;
#pragma unroll
    for (int n = 0; n < 4; ++n) {
      const int col = td * 256 + wc * 64 + n * 16 + fr;
      f32x4 v = acc[m][n];
#pragma unroll
      for (int r = 0; r < 4; ++r)
        Gp[(size_t)(row0 + r) * 512 + col] = f2bf(v[r]);
    }
  }
}

// -------- K3: reduce 8 bf16 split-K partials -> G bf16 (b XCD-local) -------
__global__ void greduce(const unsigned short* __restrict__ Gpart,
                        unsigned short* __restrict__ Gbf) {
  const int b = blockIdx.x & 7, seg = blockIdx.x >> 3;  // 128 segs per b
  const int t = threadIdx.x;
#pragma unroll
  for (int jj = 0; jj < 2; ++jj) {
    const int j4 = seg * 512 + jj * 256 + t;  // u16x4 index within batch
    float s0 = 0, s1 = 0, s2 = 0, s3 = 0;
#pragma unroll
    for (int c = 0; c < 8; ++c) {
      u16x4 v = ((const u16x4*)Gpart)[(size_t)(c * 8 + b) * 65536 + j4];
      s0 += bf2f((short)v.x); s1 += bf2f((short)v.y);
      s2 += bf2f((short)v.z); s3 += bf2f((short)v.w);
    }
    u16x4 o;
    o.x = f2bf(s0); o.y = f2bf(s1); o.z = f2bf(s2); o.w = f2bf(s3);
    ((u16x4*)Gbf)[(size_t)b * 65536 + j4] = o;
  }
}

// ------------- 2-phase double-buffered 128x128 mainloop (small GEMMs) ------
template <int KITERS>
DEVI void gemm_db(const unsigned short* gA, int strideA,
                  const unsigned short* gB, int strideB,
                  unsigned short (*lA)[4096], unsigned short (*lB)[4096],
                  int wave, int wr, int wc, int fr, int kg, f32x4 acc[4][4]) {
  const int wo = wave * 512;
#define STAGE_T(buf, kk)                                                    \
  gload16(gA + (kk) * 32, lA[buf] + wo);                                    \
  gload16(gA + (kk) * 32 + (size_t)64 * strideA, lA[buf] + wo + 2048);      \
  gload16(gB + (kk) * 32, lB[buf] + wo);                                    \
  gload16(gB + (kk) * 32 + (size_t)64 * strideB, lB[buf] + wo + 2048);
  STAGE_T(0, 0);
  __syncthreads();
  int cur = 0;
  for (int kk = 1; kk <= KITERS; ++kk) {
    if (kk < KITERS) { STAGE_T(cur ^ 1, kk); }
    bf16x8 af[4], bfv[4];
#pragma unroll
    for (int mi = 0; mi < 4; ++mi)
      af[mi] = *(const bf16x8*)&lA[cur][(wr * 64 + mi * 16 + fr) * 32 + kg * 8];
#pragma unroll
    for (int ni = 0; ni < 4; ++ni)
      bfv[ni] = *(const bf16x8*)&lB[cur][(wc * 64 + ni * 16 + fr) * 32 + kg * 8];
#pragma unroll
    for (int mi = 0; mi < 4; ++mi)
#pragma unroll
      for (int ni = 0; ni < 4; ++ni)
        acc[mi][ni] = __builtin_amdgcn_mfma_f32_16x16x32_bf16(
            af[mi], bfv[ni], acc[mi][ni], 0, 0, 0);
    __syncthreads();
    cur ^= 1;
  }
#undef STAGE_T
}

// ------- K4: T_b = Wqk @ G_b (+ fused sumsq partials), b XCD-local ---------
__launch_bounds__(256)
__global__ void tall_gemm(const unsigned short* __restrict__ Wqk,
                          const unsigned short* __restrict__ Gbf,
                          unsigned short* __restrict__ Tbf,
                          float* __restrict__ ssPart) {
  __shared__ __align__(16) unsigned short lA[2][4096];
  __shared__ __align__(16) unsigned short lB[2][4096];
  __shared__ float ssL[128][2];
  const int tid = threadIdx.x, wave = tid >> 6, lane = tid & 63;
  const int wr = wave >> 1, wc = wave & 1, fr = lane & 15, kg = lane >> 4;
  const int b = blockIdx.x;                  // dispatch_id % 8 == b
  const int colBase = blockIdx.y * 128;
  const int rowBase = blockIdx.z * 128;
  const unsigned short* Gb = Gbf + (size_t)b * 512 * 512;
  f32x4 acc[4][4] = {};
  const int sRow = wave * 16 + (lane >> 2);
  const int sK = (lane & 3) * 8;
  gemm_db<16>(Wqk + (size_t)(rowBase + sRow) * 512 + sK, 512,
              Gb + (size_t)(colBase + sRow) * 512 + sK, 512,
              lA, lB, wave, wr, wc, fr, kg, acc);
  unsigned short* Tb = Tbf + (size_t)b * 1024 * 512;
  const bool wT = rowBase < 512;
#pragma unroll
  for (int mi = 0; mi < 4; ++mi) {
    const int rbase = rowBase + wr * 64 + mi * 16 + kg * 4;
    f32x4 sacc = {0.f, 0.f, 0.f, 0.f};
#pragma unroll
    for (int ni = 0; ni < 4; ++ni) {
      const int col = colBase + wc * 64 + ni * 16 + fr;
      f32x4 v = acc[mi][ni];
#pragma unroll
      for (int r = 0; r < 4; ++r) {
        float w = bf2f((short)Wqk[(size_t)(rbase + r) * 512 + col]);
        if (wT) Tb[(size_t)(rbase + r) * 512 + col] = f2bf(v[r]);
        sacc[r] += v[r] * w;
      }
    }
#pragma unroll
    for (int o = 1; o < 16; o <<= 1) {
#pragma unroll
      for (int r = 0; r < 4; ++r) sacc[r] += __shfl_xor(sacc[r], o);
    }
    if (fr == 0) {
#pragma unroll
      for (int r = 0; r < 4; ++r)
        ssL[wr * 64 + mi * 16 + kg * 4 + r][wc] = sacc[r];
    }
  }
  __syncthreads();
  if (tid < 128)
    ssPart[((size_t)blockIdx.y * 8 + b) * 1024 + rowBase + tid] =
        ssL[tid][0] + ssL[tid][1];
}

// ------ K5: fused S = T_q @ Wk^T -> softmax -> Weff = Wproj_h @ attn -------
__global__ void s_softmax(const unsigned short* __restrict__ Tbf,
                          const unsigned short* __restrict__ Wqk,
                          const float* __restrict__ ssPart,
                          const float* __restrict__ temp,
                          const unsigned short* __restrict__ WpBf,
                          unsigned short* __restrict__ Weff) {
  __shared__ float Sl[64 * 64];
  __shared__ float invq[64], invk[64];
  __shared__ __align__(16) unsigned short atT[64 * 72];  // attn^T bf16
  const int bh = blockIdx.x, b = bh & 7, h = bh >> 3;  // b XCD-local
  const unsigned short* qbase = Tbf + (size_t)(b * 1024 + h * 64) * 512;
  const unsigned short* kbase = Wqk + (size_t)(512 + h * 64) * 512;
  const int t = threadIdx.x;
  const int wave = t >> 6, lane = t & 63;
  const int wr = wave >> 1, wc = wave & 1, fr = lane & 15, kg = lane >> 4;
  f32x4 acc[2][2] = {};
  for (int kk = 0; kk < 512; kk += 32) {
    bf16x8 a[2], bb[2];
#pragma unroll
    for (int mi = 0; mi < 2; ++mi)
      a[mi] = *(const bf16x8*)(qbase + (size_t)(wr * 32 + mi * 16 + fr) * 512 + kk + kg * 8);
#pragma unroll
    for (int ni = 0; ni < 2; ++ni)
      bb[ni] = *(const bf16x8*)(kbase + (size_t)(wc * 32 + ni * 16 + fr) * 512 + kk + kg * 8);
#pragma unroll
    for (int mi = 0; mi < 2; ++mi)
#pragma unroll
      for (int ni = 0; ni < 2; ++ni)
        acc[mi][ni] = __builtin_amdgcn_mfma_f32_16x16x32_bf16(a[mi], bb[ni], acc[mi][ni], 0, 0, 0);
  }
#pragma unroll
  for (int mi = 0; mi < 2; ++mi)
#pragma unroll
    for (int ni = 0; ni < 2; ++ni) {
      f32x4 v = acc[mi][ni];
#pragma unroll
      for (int r = 0; r < 4; ++r)
        Sl[(wr * 32 + mi * 16 + kg * 4 + r) * 64 + wc * 32 + ni * 16 + fr] = v[r];
    }
  if (t < 128) {
    const int r = (t >> 6) * 512 + h * 64 + (t & 63);
    float s = 0.f;
#pragma unroll
    for (int nt = 0; nt < 4; ++nt) s += ssPart[((size_t)nt * 8 + b) * 1024 + r];
    float inv = 1.f / fmaxf(sqrtf(s), 1e-12f);
    if (t < 64) invq[t] = inv;
    else invk[t - 64] = inv;
  }
  __syncthreads();
  const float tmp = temp[h];
  const int c = t >> 2, q4 = t & 3;
  float lg[16];
  float mx = -1e30f;
#pragma unroll
  for (int j = 0; j < 16; ++j) {
    const int d = q4 * 16 + j;
    lg[j] = Sl[c * 64 + d] * invq[c] * invk[d] * tmp;
    mx = fmaxf(mx, lg[j]);
  }
  mx = fmaxf(mx, __shfl_xor(mx, 1));
  mx = fmaxf(mx, __shfl_xor(mx, 2));
  float sum = 0.f;
#pragma unroll
  for (int j = 0; j < 16; ++j) {
    lg[j] = __expf(lg[j] - mx);
    sum += lg[j];
  }
  sum += __shfl_xor(sum, 1);
  sum += __shfl_xor(sum, 2);
  const float inv = 1.f / sum;
#pragma unroll
  for (int j = 0; j < 16; ++j)
    atT[(q4 * 16 + j) * 72 + c] = f2bf(lg[j] * inv);  // transposed bf16
  __syncthreads();
  // Weff[e][d] = sum_c WpBf[e][h*64+c] * attn[c][d];  A=[e][c], B=atT[d][c]
  bf16x8 bfrag[4][2];
#pragma unroll
  for (int n = 0; n < 4; ++n)
#pragma unroll
    for (int kk = 0; kk < 2; ++kk)
      bfrag[n][kk] =
          *(const bf16x8*)&atT[(n * 16 + fr) * 72 + kk * 32 + kg * 8];
  unsigned short* We = Weff + (size_t)b * 512 * 512 + h * 64;
#pragma unroll
  for (int m = 0; m < 8; ++m) {
    const int eA = wave * 128 + m * 16 + fr;
    bf16x8 af[2];
#pragma unroll
    for (int kk = 0; kk < 2; ++kk)
      af[kk] = *(const bf16x8*)&WpBf[(size_t)eA * 512 + h * 64 + kk * 32 + kg * 8];
    f32x4 acc4[4] = {};
#pragma unroll
    for (int kk = 0; kk < 2; ++kk)
#pragma unroll
      for (int n = 0; n < 4; ++n)
        acc4[n] = __builtin_amdgcn_mfma_f32_16x16x32_bf16(af[kk], bfrag[n][kk],
                                                          acc4[n], 0, 0, 0);
    const int e0 = wave * 128 + m * 16 + kg * 4;
#pragma unroll
    for (int n = 0; n < 4; ++n)
#pragma unroll
      for (int r = 0; r < 4; ++r)
        We[(size_t)(e0 + r) * 512 + n * 16 + fr] = f2bf(acc4[n][r]);
  }
}

// ------- K6: Wcomb[b] = Weff[b] @ Wv (= Weff · WvT^T), b XCD-local ---------
__launch_bounds__(256)
__global__ void wcomb_gemm(const unsigned short* __restrict__ WeffAll,
                           const unsigned short* __restrict__ WvT,
                           unsigned short* __restrict__ WcombAll) {
  __shared__ __align__(16) unsigned short lA[2][4096];
  __shared__ __align__(16) unsigned short lB[2][4096];
  const int tid = threadIdx.x, wave = tid >> 6, lane = tid & 63;
  const int wr = wave >> 1, wc = wave & 1, fr = lane & 15, kg = lane >> 4;
  const int b = blockIdx.x;  // dispatch_id % 8 == b
  const int colBase = blockIdx.y * 128, rowBase = blockIdx.z * 128;
  const unsigned short* A = WeffAll + (size_t)b * 512 * 512;
  f32x4 acc[4][4] = {};
  const int sRow = wave * 16 + (lane >> 2);
  const int sK = (lane & 3) * 8;
  gemm_db<16>(A + (size_t)(rowBase + sRow) * 512 + sK, 512,
              WvT + (size_t)(colBase + sRow) * 512 + sK, 512,
              lA, lB, wave, wr, wc, fr, kg, acc);
  unsigned short* Wc = WcombAll + (size_t)b * 512 * 512;
#pragma unroll
  for (int mi = 0; mi < 4; ++mi) {
    const int rbase = rowBase + wr * 64 + mi * 16 + kg * 4;
#pragma unroll
    for (int ni = 0; ni < 4; ++ni) {
      const int col = colBase + wc * 64 + ni * 16 + fr;
      f32x4 v = acc[mi][ni];
#pragma unroll
      for (int r = 0; r < 4; ++r)
        Wc[(size_t)(rbase + r) * 512 + col] = f2bf(v[r]);
    }
  }
}

// --------- K7: final = x @ Wcomb[b]^T + bproj (256^2, XCD-swizzled) --------
__launch_bounds__(512, 2)
__global__ void out_gemm(const unsigned short* __restrict__ Xbf,
                         const unsigned short* __restrict__ WcombAll,
                         const float* __restrict__ bias,
                         float* __restrict__ out) {
  __shared__ __align__(16) unsigned short ldsA[2 * 16384];
  __shared__ __align__(16) unsigned short ldsB[2 * 16384];
  int fl = blockIdx.x + 16 * (blockIdx.y + 2 * blockIdx.z);
  fl = (fl & 7) * 32 + (fl >> 3);  // b = dispatch_id % 8 -> XCD-local
  const int bxi = fl & 15, byi = (fl >> 4) & 1, b = fl >> 5;
  const int tid = threadIdx.x, wave = tid >> 6, lane = tid & 63;
  const int rowBase = bxi * 256, colBase = byi * 256;
  const unsigned short* A = Xbf + (size_t)b * 4096 * 512;
  const unsigned short* Bw = WcombAll + (size_t)b * 512 * 512;
  const int sRow = tid >> 3;
  const int kEl = 8 * ((tid & 7) ^ ((tid >> 3) & 7));
  const unsigned short* pA = A + (size_t)(rowBase + sRow) * 512 + kEl;
  const unsigned short* pB = Bw + (size_t)(colBase + sRow) * 512 + kEl;
  f32x4 acc[8][4] = {};
  gemm256_loop<8>(pA, 512, pB, 512, ldsA, ldsB, wave, lane, acc);
  const int wr = wave >> 2, wc = wave & 3;
  const int fr = lane & 15, kg = lane >> 4;
#pragma unroll
  for (int m = 0; m < 8; ++m) {
    const int row0 = rowBase + wr * 128 + m * 16 + kg * 4;
#pragma unroll
    for (int n = 0; n < 4; ++n) {
      const int col = colBase + wc * 64 + n * 16 + fr;
      const float bcol = bias[col];
      f32x4 v = acc[m][n];
#pragma unroll
      for (int r = 0; r < 4; ++r)
        out[((size_t)b * 4096 + row0 + r) * 512 + col] = v[r] + bcol;
    }
  }
}

extern "C" void kernel_launch(void* const* d_in, const int* in_sizes, int n_in,
                              void* d_out, int out_size, void* d_ws, size_t ws_size,
                              hipStream_t stream) {
  const float* x = (const float*)d_in[0];      // [8][4096][512]
  const float* Wqkv = (const float*)d_in[1];   // [1536][512]
  const float* Wproj = (const float*)d_in[2];  // [512][512]
  const float* bproj = (const float*)d_in[3];  // [512]
  const float* temp = (const float*)d_in[4];   // [8]
  float* out = (float*)d_out;

  char* ws = (char*)d_ws;
  unsigned short* Xbf = (unsigned short*)(ws + 0);            // 33,554,432
  unsigned short* xT = (unsigned short*)(ws + 33554432);      // 33,554,432
  unsigned short* Wqk = (unsigned short*)(ws + 67108864);     //  1,048,576
  unsigned short* WvT = (unsigned short*)(ws + 68157440);     //    524,288
  unsigned short* Gpart = (unsigned short*)(ws + 68681728);   // 33,554,432
  unsigned short* Gbf = (unsigned short*)(ws + 102236160);    //  4,194,304
  unsigned short* Tbf = (unsigned short*)(ws + 106430464);    //  8,388,608
  float* ssPart = (float*)(ws + 114819072);                   //    131,072
  unsigned short* Weff = (unsigned short*)(ws + 115998720);   //  4,194,304
  unsigned short* Wcomb = (unsigned short*)(ws + 120193024);  //  4,194,304
  unsigned short* WpBf = (unsigned short*)(ws + 124387328);   //    524,288
  // total: 124,911,616 B

  cast_prep<<<dim3(32, 8, 10), 256, 0, stream>>>(x, Xbf, xT, Wqkv, Wqk, WvT,
                                                 Wproj, WpBf);
  gsyrk<<<dim3(4, 8, 8), 512, 0, stream>>>(xT, Gpart);
  greduce<<<1024, 256, 0, stream>>>(Gpart, Gbf);
  tall_gemm<<<dim3(8, 4, 8), 256, 0, stream>>>(Wqk, Gbf, Tbf, ssPart);
  s_softmax<<<64, 256, 0, stream>>>(Tbf, Wqk, ssPart, temp, WpBf, Weff);
  wcomb_gemm<<<dim3(8, 4, 4), 256, 0, stream>>>(Weff, WvT, Wcomb);
  out_gemm<<<dim3(16, 2, 8), 512, 0, stream>>>(Xbf, Wcomb, bproj, out);
}